// Round 1
// baseline (231.261 us; speedup 1.0000x reference)
//
#include <hip/hip_runtime.h>
#include <hip/hip_bf16.h>

typedef __bf16 bf16x8 __attribute__((ext_vector_type(8)));
typedef float f32x4 __attribute__((ext_vector_type(4)));
using u16 = unsigned short;
using u32 = unsigned int;

#define LDSS 72  // padded LDS row stride in bf16 elems (144B: 16B-aligned, 2-way banks only)

__device__ __forceinline__ u16 f2bf(float f) {
  union { float f; u32 u; } v; v.f = f;
  u32 r = v.u + 0x7fffu + ((v.u >> 16) & 1u);   // RNE
  return (u16)(r >> 16);
}

// ---------------- cast kernels ----------------
__global__ void cast_x_kernel(const float* __restrict__ x, u16* __restrict__ xb) {
  int i = (blockIdx.x * 256 + threadIdx.x) * 8;
  float4 f0 = *(const float4*)&x[i];
  float4 f1 = *(const float4*)&x[i + 4];
  u16 u[8];
  u[0] = f2bf(f0.x); u[1] = f2bf(f0.y); u[2] = f2bf(f0.z); u[3] = f2bf(f0.w);
  u[4] = f2bf(f1.x); u[5] = f2bf(f1.y); u[6] = f2bf(f1.z); u[7] = f2bf(f1.w);
  *(uint4*)&xb[i] = *(uint4*)u;
}

// weights (512x512, stored in,out) -> bf16 transposed (out,in)
__global__ void cast_wT_kernel(const float* __restrict__ w0, const float* __restrict__ w1,
                               const float* __restrict__ w2, const float* __restrict__ w3,
                               u16* __restrict__ t0, u16* __restrict__ t1,
                               u16* __restrict__ t2, u16* __restrict__ t3) {
  int i = blockIdx.x * 256 + threadIdx.x;     // 0 .. 4*262144
  int wi = i >> 18;
  int r = i & 262143;
  int row = r >> 9, col = r & 511;
  const float* w; u16* t;
  if (wi == 0)      { w = w0; t = t0; }
  else if (wi == 1) { w = w1; t = t1; }
  else if (wi == 2) { w = w2; t = t2; }
  else              { w = w3; t = t3; }
  t[col * 512 + row] = f2bf(w[r]);
}

// ---------------- QKV projection GEMM ----------------
// y = x @ w + b ; 64x64 tile, 4 waves (2x2), BK=64, mfma 16x16x32 bf16
__global__ __launch_bounds__(256) void proj_kernel(
    const u16* __restrict__ xb,
    const u16* __restrict__ wqT, const u16* __restrict__ wkT, const u16* __restrict__ wvT,
    const float* __restrict__ bq, const float* __restrict__ bk, const float* __restrict__ bv,
    u16* __restrict__ Q, u16* __restrict__ K, u16* __restrict__ V) {
  __shared__ u16 Alds[64 * LDSS];
  __shared__ u16 Blds[64 * LDSS];
  int which = blockIdx.z;
  const u16* wT; const float* bias; u16* out;
  if (which == 0)      { wT = wqT; bias = bq; out = Q; }
  else if (which == 1) { wT = wkT; bias = bk; out = K; }
  else                 { wT = wvT; bias = bv; out = V; }

  int m0 = blockIdx.y * 64;
  int n0 = blockIdx.x * 64;
  int tid = threadIdx.x;
  int lane = tid & 63, w = tid >> 6;
  int wm = w >> 1, wn = w & 1;
  int l15 = lane & 15, l4 = lane >> 4;

  f32x4 acc[2][2] = {};
  for (int k0 = 0; k0 < 512; k0 += 64) {
    __syncthreads();
#pragma unroll
    for (int c = tid; c < 512; c += 256) {
      int row = c >> 3, c8 = (c & 7) * 8;
      *(uint4*)&Alds[row * LDSS + c8] = *(const uint4*)&xb[(m0 + row) * 512 + k0 + c8];
      *(uint4*)&Blds[row * LDSS + c8] = *(const uint4*)&wT[(n0 + row) * 512 + k0 + c8];
    }
    __syncthreads();
#pragma unroll
    for (int kk = 0; kk < 2; kk++) {
      bf16x8 a[2], b[2];
#pragma unroll
      for (int f = 0; f < 2; f++) {
        a[f] = *(const bf16x8*)&Alds[(wm * 32 + f * 16 + l15) * LDSS + kk * 32 + l4 * 8];
        b[f] = *(const bf16x8*)&Blds[(wn * 32 + f * 16 + l15) * LDSS + kk * 32 + l4 * 8];
      }
#pragma unroll
      for (int fm = 0; fm < 2; fm++)
#pragma unroll
        for (int fn = 0; fn < 2; fn++)
          acc[fm][fn] = __builtin_amdgcn_mfma_f32_16x16x32_bf16(a[fm], b[fn], acc[fm][fn], 0, 0, 0);
    }
  }
  // write to (b, head, n, dh) bf16
  int bidx = m0 >> 11;
  int head = n0 >> 6;
#pragma unroll
  for (int fm = 0; fm < 2; fm++)
#pragma unroll
    for (int fn = 0; fn < 2; fn++)
#pragma unroll
      for (int r = 0; r < 4; r++) {
        int row = wm * 32 + fm * 16 + l4 * 4 + r;
        int col = wn * 32 + fn * 16 + l15;
        int nrow = (m0 & 2047) + row;
        float vv = acc[fm][fn][r] + bias[n0 + col];
        out[(((size_t)(bidx * 8 + head) * 2048) + nrow) * 64 + col] = f2bf(vv);
      }
}

// ---------------- flash attention ----------------
// block = (qtile, h, b); 4 waves x 16 q-rows; KV tiles of 64
__global__ __launch_bounds__(256) void attn_kernel(
    const u16* __restrict__ Q, const u16* __restrict__ K, const u16* __restrict__ V,
    const float* __restrict__ bias, u16* __restrict__ O) {
  __shared__ u16 Klds[64 * LDSS];
  __shared__ u16 Vtlds[64 * LDSS];
  __shared__ u16 Plds[4][16 * LDSS];

  int qt = blockIdx.x, h = blockIdx.y, b = blockIdx.z;
  int tid = threadIdx.x;
  int lane = tid & 63, w = tid >> 6;
  int l15 = lane & 15, l4 = lane >> 4;
  int q0 = qt * 64;

  const u16* Qbh = Q + (size_t)(b * 8 + h) * 2048 * 64;
  const u16* Kbh = K + (size_t)(b * 8 + h) * 2048 * 64;
  const u16* Vbh = V + (size_t)(b * 8 + h) * 2048 * 64;
  const float* biasb = bias + (size_t)b * 2048 * 2048;

  // Q A-fragments, rows q0 + w*16 + l15
  bf16x8 aq[2];
#pragma unroll
  for (int kk = 0; kk < 2; kk++)
    aq[kk] = *(const bf16x8*)&Qbh[(q0 + w * 16 + l15) * 64 + kk * 32 + l4 * 8];

  f32x4 o[4] = {};
  float mrow[4], lrow[4];
#pragma unroll
  for (int r = 0; r < 4; r++) { mrow[r] = -1e30f; lrow[r] = 0.f; }
  int qrowbase = q0 + w * 16 + l4 * 4;

  for (int t = 0; t < 32; t++) {
    __syncthreads();
    // stage K (row-major) and V (transposed)
#pragma unroll
    for (int c = tid; c < 512; c += 256) {
      int row = c >> 3, c8 = (c & 7) * 8;
      *(uint4*)&Klds[row * LDSS + c8] = *(const uint4*)&Kbh[(t * 64 + row) * 64 + c8];
      u16 vv[8];
      *(uint4*)vv = *(const uint4*)&Vbh[(t * 64 + row) * 64 + c8];
#pragma unroll
      for (int j = 0; j < 8; j++)
        Vtlds[(c8 + j) * LDSS + row] = vv[j];
    }
    __syncthreads();

    // S = Q K^T  (16x64 per wave)
    f32x4 s[4] = {};
#pragma unroll
    for (int kk = 0; kk < 2; kk++)
#pragma unroll
      for (int fj = 0; fj < 4; fj++) {
        bf16x8 kb = *(const bf16x8*)&Klds[(fj * 16 + l15) * LDSS + kk * 32 + l4 * 8];
        s[fj] = __builtin_amdgcn_mfma_f32_16x16x32_bf16(aq[kk], kb, s[fj], 0, 0, 0);
      }

    // scale + bias (f32)
    float sv[4][4];
#pragma unroll
    for (int fj = 0; fj < 4; fj++)
#pragma unroll
      for (int r = 0; r < 4; r++) {
        float bval = biasb[(size_t)(qrowbase + r) * 2048 + t * 64 + fj * 16 + l15];
        sv[fj][r] = s[fj][r] * 0.125f + bval;
      }

    // online softmax (per lane: 4 rows)
    float mt[4];
#pragma unroll
    for (int r = 0; r < 4; r++) {
      float m = fmaxf(fmaxf(sv[0][r], sv[1][r]), fmaxf(sv[2][r], sv[3][r]));
#pragma unroll
      for (int d = 1; d < 16; d <<= 1) m = fmaxf(m, __shfl_xor(m, d));
      mt[r] = m;
    }
    float p[4][4];
#pragma unroll
    for (int r = 0; r < 4; r++) {
      float mnew = fmaxf(mrow[r], mt[r]);
      float corr = __expf(mrow[r] - mnew);
      mrow[r] = mnew;
      float sum = 0.f;
#pragma unroll
      for (int fj = 0; fj < 4; fj++) {
        p[fj][r] = __expf(sv[fj][r] - mnew);
        sum += p[fj][r];
      }
#pragma unroll
      for (int d = 1; d < 16; d <<= 1) sum += __shfl_xor(sum, d);
      lrow[r] = lrow[r] * corr + sum;
#pragma unroll
      for (int fo = 0; fo < 4; fo++) o[fo][r] *= corr;
    }

    // P -> LDS (bf16, per-wave buffer; wave-internal RAW handled by lgkmcnt)
#pragma unroll
    for (int fj = 0; fj < 4; fj++)
#pragma unroll
      for (int r = 0; r < 4; r++)
        Plds[w][(l4 * 4 + r) * LDSS + fj * 16 + l15] = f2bf(p[fj][r]);

    // O += P @ V
#pragma unroll
    for (int kk = 0; kk < 2; kk++) {
      bf16x8 ap = *(const bf16x8*)&Plds[w][l15 * LDSS + kk * 32 + l4 * 8];
#pragma unroll
      for (int fo = 0; fo < 4; fo++) {
        bf16x8 bv_ = *(const bf16x8*)&Vtlds[(fo * 16 + l15) * LDSS + kk * 32 + l4 * 8];
        o[fo] = __builtin_amdgcn_mfma_f32_16x16x32_bf16(ap, bv_, o[fo], 0, 0, 0);
      }
    }
  }

  // normalize + write O in (b, n, h*64+d) bf16
#pragma unroll
  for (int fo = 0; fo < 4; fo++)
#pragma unroll
    for (int r = 0; r < 4; r++) {
      float vv = o[fo][r] / lrow[r];
      int nrow = q0 + w * 16 + l4 * 4 + r;
      O[((size_t)(b * 2048 + nrow)) * 512 + h * 64 + fo * 16 + l15] = f2bf(vv);
    }
}

// ---------------- output projection ----------------
__global__ __launch_bounds__(256) void outproj_kernel(
    const u16* __restrict__ Ob, const u16* __restrict__ woT,
    const float* __restrict__ bo, float* __restrict__ out) {
  __shared__ u16 Alds[64 * LDSS];
  __shared__ u16 Blds[64 * LDSS];
  int m0 = blockIdx.y * 64;
  int n0 = blockIdx.x * 64;
  int tid = threadIdx.x;
  int lane = tid & 63, w = tid >> 6;
  int wm = w >> 1, wn = w & 1;
  int l15 = lane & 15, l4 = lane >> 4;

  f32x4 acc[2][2] = {};
  for (int k0 = 0; k0 < 512; k0 += 64) {
    __syncthreads();
#pragma unroll
    for (int c = tid; c < 512; c += 256) {
      int row = c >> 3, c8 = (c & 7) * 8;
      *(uint4*)&Alds[row * LDSS + c8] = *(const uint4*)&Ob[(m0 + row) * 512 + k0 + c8];
      *(uint4*)&Blds[row * LDSS + c8] = *(const uint4*)&woT[(n0 + row) * 512 + k0 + c8];
    }
    __syncthreads();
#pragma unroll
    for (int kk = 0; kk < 2; kk++) {
      bf16x8 a[2], bfr[2];
#pragma unroll
      for (int f = 0; f < 2; f++) {
        a[f] = *(const bf16x8*)&Alds[(wm * 32 + f * 16 + l15) * LDSS + kk * 32 + l4 * 8];
        bfr[f] = *(const bf16x8*)&Blds[(wn * 32 + f * 16 + l15) * LDSS + kk * 32 + l4 * 8];
      }
#pragma unroll
      for (int fm = 0; fm < 2; fm++)
#pragma unroll
        for (int fn = 0; fn < 2; fn++)
          acc[fm][fn] = __builtin_amdgcn_mfma_f32_16x16x32_bf16(a[fm], bfr[fn], acc[fm][fn], 0, 0, 0);
    }
  }
#pragma unroll
  for (int fm = 0; fm < 2; fm++)
#pragma unroll
    for (int fn = 0; fn < 2; fn++)
#pragma unroll
      for (int r = 0; r < 4; r++) {
        int row = wm * 32 + fm * 16 + l4 * 4 + r;
        int col = wn * 32 + fn * 16 + l15;
        out[(size_t)(m0 + row) * 512 + n0 + col] = acc[fm][fn][r] + bo[n0 + col];
      }
}

extern "C" void kernel_launch(void* const* d_in, const int* in_sizes, int n_in,
                              void* d_out, int out_size, void* d_ws, size_t ws_size,
                              hipStream_t stream) {
  const float* x    = (const float*)d_in[0];
  const float* bias = (const float*)d_in[1];
  const float* wq   = (const float*)d_in[2];
  const float* bq   = (const float*)d_in[3];
  const float* wk   = (const float*)d_in[4];
  const float* bk   = (const float*)d_in[5];
  const float* wv   = (const float*)d_in[6];
  const float* bv   = (const float*)d_in[7];
  const float* wo   = (const float*)d_in[8];
  const float* bo   = (const float*)d_in[9];
  float* out = (float*)d_out;

  char* ws = (char*)d_ws;
  u16* xb  = (u16*)(ws + 0);
  u16* wqT = (u16*)(ws + 8388608);
  u16* wkT = (u16*)(ws + 8912896);
  u16* wvT = (u16*)(ws + 9437184);
  u16* woT = (u16*)(ws + 9961472);
  u16* Qb  = (u16*)(ws + 10485760);
  u16* Kb  = (u16*)(ws + 18874368);
  u16* Vb  = (u16*)(ws + 27262976);
  u16* Ob  = (u16*)(ws + 35651584);

  hipLaunchKernelGGL(cast_x_kernel, dim3(2048), dim3(256), 0, stream, x, xb);
  hipLaunchKernelGGL(cast_wT_kernel, dim3(4096), dim3(256), 0, stream,
                     wq, wk, wv, wo, wqT, wkT, wvT, woT);
  hipLaunchKernelGGL(proj_kernel, dim3(8, 128, 3), dim3(256), 0, stream,
                     xb, wqT, wkT, wvT, bq, bk, bv, Qb, Kb, Vb);
  hipLaunchKernelGGL(attn_kernel, dim3(32, 8, 4), dim3(256), 0, stream,
                     Qb, Kb, Vb, bias, Ob);
  hipLaunchKernelGGL(outproj_kernel, dim3(8, 128), dim3(256), 0, stream,
                     Ob, woT, bo, out);
}

// Round 2
// 162.172 us; speedup vs baseline: 1.4260x; 1.4260x over previous
//
#include <hip/hip_runtime.h>
#include <hip/hip_bf16.h>

typedef __bf16 bf16x8 __attribute__((ext_vector_type(8)));
typedef float f32x4 __attribute__((ext_vector_type(4)));
using u16 = unsigned short;
using u32 = unsigned int;

#define LDSS 72  // padded LDS row stride in bf16 elems

__device__ __forceinline__ u16 f2bf(float f) {
  union { float f; u32 u; } v; v.f = f;
  u32 r = v.u + 0x7fffu + ((v.u >> 16) & 1u);   // RNE
  return (u16)(r >> 16);
}

__device__ __forceinline__ u32 cvt_pk_bf16(float lo, float hi) {
  u32 r;
  asm("v_cvt_pk_bf16_f32 %0, %1, %2" : "=v"(r) : "v"(lo), "v"(hi));
  return r;
}

// ---------------- cast kernels ----------------
__global__ void cast_x_kernel(const float* __restrict__ x, u16* __restrict__ xb) {
  int i = (blockIdx.x * 256 + threadIdx.x) * 8;
  float4 f0 = *(const float4*)&x[i];
  float4 f1 = *(const float4*)&x[i + 4];
  u16 u[8];
  u[0] = f2bf(f0.x); u[1] = f2bf(f0.y); u[2] = f2bf(f0.z); u[3] = f2bf(f0.w);
  u[4] = f2bf(f1.x); u[5] = f2bf(f1.y); u[6] = f2bf(f1.z); u[7] = f2bf(f1.w);
  *(uint4*)&xb[i] = *(uint4*)u;
}

// weights (512x512, stored in,out) -> bf16 transposed (out,in)
__global__ void cast_wT_kernel(const float* __restrict__ w0, const float* __restrict__ w1,
                               const float* __restrict__ w2, const float* __restrict__ w3,
                               u16* __restrict__ t0, u16* __restrict__ t1,
                               u16* __restrict__ t2, u16* __restrict__ t3) {
  int i = blockIdx.x * 256 + threadIdx.x;
  int wi = i >> 18;
  int r = i & 262143;
  int row = r >> 9, col = r & 511;
  const float* w; u16* t;
  if (wi == 0)      { w = w0; t = t0; }
  else if (wi == 1) { w = w1; t = t1; }
  else if (wi == 2) { w = w2; t = t2; }
  else              { w = w3; t = t3; }
  t[col * 512 + row] = f2bf(w[r]);
}

// ---------------- QKV projection GEMM ----------------
// Q,K: y = x @ w + b -> (b,h,n,dh) row-major.
// V: operand-swapped MFMA -> output tile already transposed -> Vt (b,h,dh,n).
__global__ __launch_bounds__(256) void proj_kernel(
    const u16* __restrict__ xb,
    const u16* __restrict__ wqT, const u16* __restrict__ wkT, const u16* __restrict__ wvT,
    const float* __restrict__ bq, const float* __restrict__ bk, const float* __restrict__ bv,
    u16* __restrict__ Q, u16* __restrict__ K, u16* __restrict__ Vt) {
  __shared__ u16 Alds[64 * LDSS];
  __shared__ u16 Blds[64 * LDSS];
  int which = blockIdx.z;
  const u16* wT; const float* bias; u16* out;
  if (which == 0)      { wT = wqT; bias = bq; out = Q; }
  else if (which == 1) { wT = wkT; bias = bk; out = K; }
  else                 { wT = wvT; bias = bv; out = Vt; }

  int m0 = blockIdx.y * 64;
  int n0 = blockIdx.x * 64;
  int tid = threadIdx.x;
  int lane = tid & 63, w = tid >> 6;
  int wm = w >> 1, wn = w & 1;
  int l15 = lane & 15, l4 = lane >> 4;

  f32x4 acc[2][2] = {};
  for (int k0 = 0; k0 < 512; k0 += 64) {
    __syncthreads();
#pragma unroll
    for (int c = tid; c < 512; c += 256) {
      int row = c >> 3, c8 = (c & 7) * 8;
      *(uint4*)&Alds[row * LDSS + c8] = *(const uint4*)&xb[(m0 + row) * 512 + k0 + c8];
      *(uint4*)&Blds[row * LDSS + c8] = *(const uint4*)&wT[(n0 + row) * 512 + k0 + c8];
    }
    __syncthreads();
#pragma unroll
    for (int kk = 0; kk < 2; kk++) {
      bf16x8 a[2], b[2];
#pragma unroll
      for (int f = 0; f < 2; f++) {
        a[f] = *(const bf16x8*)&Alds[(wm * 32 + f * 16 + l15) * LDSS + kk * 32 + l4 * 8];
        b[f] = *(const bf16x8*)&Blds[(wn * 32 + f * 16 + l15) * LDSS + kk * 32 + l4 * 8];
      }
#pragma unroll
      for (int fm = 0; fm < 2; fm++)
#pragma unroll
        for (int fn = 0; fn < 2; fn++) {
          if (which == 2)
            acc[fm][fn] = __builtin_amdgcn_mfma_f32_16x16x32_bf16(b[fn], a[fm], acc[fm][fn], 0, 0, 0);
          else
            acc[fm][fn] = __builtin_amdgcn_mfma_f32_16x16x32_bf16(a[fm], b[fn], acc[fm][fn], 0, 0, 0);
        }
    }
  }
  int bidx = m0 >> 11;
  int head = n0 >> 6;
  if (which == 2) {
    // D row = feature(dh), col = x-row(n): write Vt[(b,h,dh), n]
#pragma unroll
    for (int fm = 0; fm < 2; fm++)
#pragma unroll
      for (int fn = 0; fn < 2; fn++)
#pragma unroll
        for (int r = 0; r < 4; r++) {
          int drow = wn * 32 + fn * 16 + l4 * 4 + r;   // feature within 64
          int col  = wm * 32 + fm * 16 + l15;          // x-row within 64
          float vv = acc[fm][fn][r] + bias[n0 + drow];
          out[((size_t)(bidx * 8 + head) * 64 + drow) * 2048 + (m0 & 2047) + col] = f2bf(vv);
        }
  } else {
#pragma unroll
    for (int fm = 0; fm < 2; fm++)
#pragma unroll
      for (int fn = 0; fn < 2; fn++)
#pragma unroll
        for (int r = 0; r < 4; r++) {
          int row = wm * 32 + fm * 16 + l4 * 4 + r;
          int col = wn * 32 + fn * 16 + l15;
          int nrow = (m0 & 2047) + row;
          float vv = acc[fm][fn][r] + bias[n0 + col];
          out[(((size_t)(bidx * 8 + head) * 2048) + nrow) * 64 + col] = f2bf(vv);
        }
  }
}

// ---------------- flash attention (swapped QK^T, in-register P) ----------------
// block = (qtile of 128 rows, h, b); 8 waves x 16 q-rows; KV tiles of 64
__global__ __launch_bounds__(512, 4) void attn_kernel(
    const u16* __restrict__ Q, const u16* __restrict__ K, const u16* __restrict__ Vt,
    const float* __restrict__ bias, u16* __restrict__ O) {
  __shared__ u16 Klds[64 * LDSS];
  __shared__ u16 Vtlds[64 * LDSS];

  int qt = blockIdx.x, h = blockIdx.y, b = blockIdx.z;
  int tid = threadIdx.x;
  int lane = tid & 63, w = tid >> 6;
  int l15 = lane & 15, l4 = lane >> 4;
  int qrow = qt * 128 + w * 16 + l15;

  const u16* Qbh  = Q  + (size_t)(b * 8 + h) * 2048 * 64;
  const u16* Kbh  = K  + (size_t)(b * 8 + h) * 2048 * 64;
  const u16* Vtbh = Vt + (size_t)(b * 8 + h) * 64 * 2048;
  const float* biasrow = bias + (size_t)b * 2048 * 2048 + (size_t)qrow * 2048;

  bf16x8 aq[2];
#pragma unroll
  for (int kk = 0; kk < 2; kk++)
    aq[kk] = *(const bf16x8*)&Qbh[qrow * 64 + kk * 32 + l4 * 8];

  f32x4 o[4] = {};
  float mrow = -1e30f, lrow = 0.f;

  int srcA = (lane & 16) * 2 + l15;   // ((l4&1)*2)*16 + l15
  bool hiF = (l4 >> 1) != 0;

  for (int t = 0; t < 32; t++) {
    __syncthreads();
    {
      int row = tid >> 3, c8 = (tid & 7) * 8;
      *(uint4*)&Klds[row * LDSS + c8]  = *(const uint4*)&Kbh[(t * 64 + row) * 64 + c8];
      *(uint4*)&Vtlds[row * LDSS + c8] = *(const uint4*)&Vtbh[row * 2048 + t * 64 + c8];
    }
    __syncthreads();

    // S^T = K·Q^T : lane holds S[q=l15][k = fj*16 + l4*4 + r]
    f32x4 s[4] = {};
#pragma unroll
    for (int kk = 0; kk < 2; kk++)
#pragma unroll
      for (int fj = 0; fj < 4; fj++) {
        bf16x8 kf = *(const bf16x8*)&Klds[(fj * 16 + l15) * LDSS + kk * 32 + l4 * 8];
        s[fj] = __builtin_amdgcn_mfma_f32_16x16x32_bf16(kf, aq[kk], s[fj], 0, 0, 0);
      }

    // scale + bias (vectorized f32 loads: 4 consecutive k per lane)
    float m = -1e30f;
#pragma unroll
    for (int fj = 0; fj < 4; fj++) {
      float4 bb = *(const float4*)&biasrow[t * 64 + fj * 16 + l4 * 4];
#pragma unroll
      for (int r = 0; r < 4; r++) {
        s[fj][r] = s[fj][r] * 0.125f + ((const float*)&bb)[r];
        m = fmaxf(m, s[fj][r]);
      }
    }
    m = fmaxf(m, __shfl_xor(m, 16));
    m = fmaxf(m, __shfl_xor(m, 32));
    float mnew = fmaxf(mrow, m);
    float corr = __expf(mrow - mnew);
    mrow = mnew;

    u32 pk[4][2];
    float sum = 0.f;
#pragma unroll
    for (int fj = 0; fj < 4; fj++) {
      float p0 = __expf(s[fj][0] - mnew);
      float p1 = __expf(s[fj][1] - mnew);
      float p2 = __expf(s[fj][2] - mnew);
      float p3 = __expf(s[fj][3] - mnew);
      sum += (p0 + p1) + (p2 + p3);
      pk[fj][0] = cvt_pk_bf16(p0, p1);
      pk[fj][1] = cvt_pk_bf16(p2, p3);
    }
    sum += __shfl_xor(sum, 16);
    sum += __shfl_xor(sum, 32);
    lrow = lrow * corr + sum;
#pragma unroll
    for (int fo = 0; fo < 4; fo++)
#pragma unroll
      for (int r = 0; r < 4; r++) o[fo][r] *= corr;

    // redistribute P^T -> PV B-fragments fully in-register
#pragma unroll
    for (int kk = 0; kk < 2; kk++) {
      u32 a0 = __shfl((int)pk[2 * kk][0],     srcA);
      u32 b0 = __shfl((int)pk[2 * kk + 1][0], srcA);
      u32 a1 = __shfl((int)pk[2 * kk][1],     srcA);
      u32 b1 = __shfl((int)pk[2 * kk + 1][1], srcA);
      u32 a2 = __shfl((int)pk[2 * kk][0],     srcA + 16);
      u32 b2 = __shfl((int)pk[2 * kk + 1][0], srcA + 16);
      u32 a3 = __shfl((int)pk[2 * kk][1],     srcA + 16);
      u32 b3 = __shfl((int)pk[2 * kk + 1][1], srcA + 16);
      union { u32 u[4]; bf16x8 v; } pu;
      pu.u[0] = hiF ? b0 : a0;
      pu.u[1] = hiF ? b1 : a1;
      pu.u[2] = hiF ? b2 : a2;
      pu.u[3] = hiF ? b3 : a3;
#pragma unroll
      for (int fo = 0; fo < 4; fo++) {
        bf16x8 vt = *(const bf16x8*)&Vtlds[(fo * 16 + l15) * LDSS + kk * 32 + l4 * 8];
        o[fo] = __builtin_amdgcn_mfma_f32_16x16x32_bf16(vt, pu.v, o[fo], 0, 0, 0);
      }
    }
  }

  // normalize + write O (b, n, h*64+d) bf16, packed u32 stores
  float inv = 1.0f / lrow;
  size_t obase = (size_t)(b * 2048 + qrow) * 512 + h * 64;
#pragma unroll
  for (int fo = 0; fo < 4; fo++) {
    u32 wlo = cvt_pk_bf16(o[fo][0] * inv, o[fo][1] * inv);
    u32 whi = cvt_pk_bf16(o[fo][2] * inv, o[fo][3] * inv);
    *(u32*)&O[obase + fo * 16 + l4 * 4]     = wlo;
    *(u32*)&O[obase + fo * 16 + l4 * 4 + 2] = whi;
  }
}

// ---------------- output projection ----------------
__global__ __launch_bounds__(256) void outproj_kernel(
    const u16* __restrict__ Ob, const u16* __restrict__ woT,
    const float* __restrict__ bo, float* __restrict__ out) {
  __shared__ u16 Alds[64 * LDSS];
  __shared__ u16 Blds[64 * LDSS];
  int m0 = blockIdx.y * 64;
  int n0 = blockIdx.x * 64;
  int tid = threadIdx.x;
  int lane = tid & 63, w = tid >> 6;
  int wm = w >> 1, wn = w & 1;
  int l15 = lane & 15, l4 = lane >> 4;

  f32x4 acc[2][2] = {};
  for (int k0 = 0; k0 < 512; k0 += 64) {
    __syncthreads();
#pragma unroll
    for (int c = tid; c < 512; c += 256) {
      int row = c >> 3, c8 = (c & 7) * 8;
      *(uint4*)&Alds[row * LDSS + c8] = *(const uint4*)&Ob[(m0 + row) * 512 + k0 + c8];
      *(uint4*)&Blds[row * LDSS + c8] = *(const uint4*)&woT[(n0 + row) * 512 + k0 + c8];
    }
    __syncthreads();
#pragma unroll
    for (int kk = 0; kk < 2; kk++) {
      bf16x8 a[2], bfr[2];
#pragma unroll
      for (int f = 0; f < 2; f++) {
        a[f] = *(const bf16x8*)&Alds[(wm * 32 + f * 16 + l15) * LDSS + kk * 32 + l4 * 8];
        bfr[f] = *(const bf16x8*)&Blds[(wn * 32 + f * 16 + l15) * LDSS + kk * 32 + l4 * 8];
      }
#pragma unroll
      for (int fm = 0; fm < 2; fm++)
#pragma unroll
        for (int fn = 0; fn < 2; fn++)
          acc[fm][fn] = __builtin_amdgcn_mfma_f32_16x16x32_bf16(a[fm], bfr[fn], acc[fm][fn], 0, 0, 0);
    }
  }
#pragma unroll
  for (int fm = 0; fm < 2; fm++)
#pragma unroll
    for (int fn = 0; fn < 2; fn++)
#pragma unroll
      for (int r = 0; r < 4; r++) {
        int row = wm * 32 + fm * 16 + l4 * 4 + r;
        int col = wn * 32 + fn * 16 + l15;
        out[(size_t)(m0 + row) * 512 + n0 + col] = acc[fm][fn][r] + bo[n0 + col];
      }
}

extern "C" void kernel_launch(void* const* d_in, const int* in_sizes, int n_in,
                              void* d_out, int out_size, void* d_ws, size_t ws_size,
                              hipStream_t stream) {
  const float* x    = (const float*)d_in[0];
  const float* bias = (const float*)d_in[1];
  const float* wq   = (const float*)d_in[2];
  const float* bq   = (const float*)d_in[3];
  const float* wk   = (const float*)d_in[4];
  const float* bk   = (const float*)d_in[5];
  const float* wv   = (const float*)d_in[6];
  const float* bv   = (const float*)d_in[7];
  const float* wo   = (const float*)d_in[8];
  const float* bo   = (const float*)d_in[9];
  float* out = (float*)d_out;

  char* ws = (char*)d_ws;
  u16* xb  = (u16*)(ws + 0);
  u16* wqT = (u16*)(ws + 8388608);
  u16* wkT = (u16*)(ws + 8912896);
  u16* wvT = (u16*)(ws + 9437184);
  u16* woT = (u16*)(ws + 9961472);
  u16* Qb  = (u16*)(ws + 10485760);
  u16* Kb  = (u16*)(ws + 18874368);
  u16* VtB = (u16*)(ws + 27262976);
  u16* Ob  = (u16*)(ws + 35651584);

  hipLaunchKernelGGL(cast_x_kernel, dim3(2048), dim3(256), 0, stream, x, xb);
  hipLaunchKernelGGL(cast_wT_kernel, dim3(4096), dim3(256), 0, stream,
                     wq, wk, wv, wo, wqT, wkT, wvT, woT);
  hipLaunchKernelGGL(proj_kernel, dim3(8, 128, 3), dim3(256), 0, stream,
                     xb, wqT, wkT, wvT, bq, bk, bv, Qb, Kb, VtB);
  hipLaunchKernelGGL(attn_kernel, dim3(16, 8, 4), dim3(512), 0, stream,
                     Qb, Kb, VtB, bias, Ob);
  hipLaunchKernelGGL(outproj_kernel, dim3(8, 128), dim3(256), 0, stream,
                     Ob, woT, bo, out);
}

// Round 4
// 154.280 us; speedup vs baseline: 1.4990x; 1.0512x over previous
//
#include <hip/hip_runtime.h>
#include <hip/hip_bf16.h>

typedef __bf16 bf16x8 __attribute__((ext_vector_type(8)));
typedef float f32x4 __attribute__((ext_vector_type(4)));
using u16 = unsigned short;
using u32 = unsigned int;

#define LDSS 72  // padded LDS row stride in bf16 elems

__device__ __forceinline__ u16 f2bf(float f) {
  union { float f; u32 u; } v; v.f = f;
  u32 r = v.u + 0x7fffu + ((v.u >> 16) & 1u);   // RNE
  return (u16)(r >> 16);
}

__device__ __forceinline__ u32 cvt_pk_bf16(float lo, float hi) {
  u32 r;
  asm("v_cvt_pk_bf16_f32 %0, %1, %2" : "=v"(r) : "v"(lo), "v"(hi));
  return r;
}

// ---------------- cast kernels ----------------
__global__ void cast_x_kernel(const float* __restrict__ x, u16* __restrict__ xb) {
  int i = (blockIdx.x * 256 + threadIdx.x) * 8;
  float4 f0 = *(const float4*)&x[i];
  float4 f1 = *(const float4*)&x[i + 4];
  u16 u[8];
  u[0] = f2bf(f0.x); u[1] = f2bf(f0.y); u[2] = f2bf(f0.z); u[3] = f2bf(f0.w);
  u[4] = f2bf(f1.x); u[5] = f2bf(f1.y); u[6] = f2bf(f1.z); u[7] = f2bf(f1.w);
  *(uint4*)&xb[i] = *(uint4*)u;
}

// weights (512x512, stored in,out) -> bf16 transposed (out,in)
__global__ void cast_wT_kernel(const float* __restrict__ w0, const float* __restrict__ w1,
                               const float* __restrict__ w2, const float* __restrict__ w3,
                               u16* __restrict__ t0, u16* __restrict__ t1,
                               u16* __restrict__ t2, u16* __restrict__ t3) {
  int i = blockIdx.x * 256 + threadIdx.x;
  int wi = i >> 18;
  int r = i & 262143;
  int row = r >> 9, col = r & 511;
  const float* w; u16* t;
  if (wi == 0)      { w = w0; t = t0; }
  else if (wi == 1) { w = w1; t = t1; }
  else if (wi == 2) { w = w2; t = t2; }
  else              { w = w3; t = t3; }
  t[col * 512 + row] = f2bf(w[r]);
}

// ---------------- QKV projection GEMM ----------------
__global__ __launch_bounds__(256) void proj_kernel(
    const u16* __restrict__ xb,
    const u16* __restrict__ wqT, const u16* __restrict__ wkT, const u16* __restrict__ wvT,
    const float* __restrict__ bq, const float* __restrict__ bk, const float* __restrict__ bv,
    u16* __restrict__ Q, u16* __restrict__ K, u16* __restrict__ Vt) {
  __shared__ u16 Alds[64 * LDSS];
  __shared__ u16 Blds[64 * LDSS];
  int which = blockIdx.z;
  const u16* wT; const float* bias; u16* out;
  if (which == 0)      { wT = wqT; bias = bq; out = Q; }
  else if (which == 1) { wT = wkT; bias = bk; out = K; }
  else                 { wT = wvT; bias = bv; out = Vt; }

  int m0 = blockIdx.y * 64;
  int n0 = blockIdx.x * 64;
  int tid = threadIdx.x;
  int lane = tid & 63, w = tid >> 6;
  int wm = w >> 1, wn = w & 1;
  int l15 = lane & 15, l4 = lane >> 4;

  f32x4 acc[2][2] = {};
  for (int k0 = 0; k0 < 512; k0 += 64) {
    __syncthreads();
#pragma unroll
    for (int c = tid; c < 512; c += 256) {
      int row = c >> 3, c8 = (c & 7) * 8;
      *(uint4*)&Alds[row * LDSS + c8] = *(const uint4*)&xb[(m0 + row) * 512 + k0 + c8];
      *(uint4*)&Blds[row * LDSS + c8] = *(const uint4*)&wT[(n0 + row) * 512 + k0 + c8];
    }
    __syncthreads();
#pragma unroll
    for (int kk = 0; kk < 2; kk++) {
      bf16x8 a[2], b[2];
#pragma unroll
      for (int f = 0; f < 2; f++) {
        a[f] = *(const bf16x8*)&Alds[(wm * 32 + f * 16 + l15) * LDSS + kk * 32 + l4 * 8];
        b[f] = *(const bf16x8*)&Blds[(wn * 32 + f * 16 + l15) * LDSS + kk * 32 + l4 * 8];
      }
#pragma unroll
      for (int fm = 0; fm < 2; fm++)
#pragma unroll
        for (int fn = 0; fn < 2; fn++) {
          if (which == 2)
            acc[fm][fn] = __builtin_amdgcn_mfma_f32_16x16x32_bf16(b[fn], a[fm], acc[fm][fn], 0, 0, 0);
          else
            acc[fm][fn] = __builtin_amdgcn_mfma_f32_16x16x32_bf16(a[fm], b[fn], acc[fm][fn], 0, 0, 0);
        }
    }
  }
  int bidx = m0 >> 11;
  int head = n0 >> 6;
  if (which == 2) {
#pragma unroll
    for (int fm = 0; fm < 2; fm++)
#pragma unroll
      for (int fn = 0; fn < 2; fn++)
#pragma unroll
        for (int r = 0; r < 4; r++) {
          int drow = wn * 32 + fn * 16 + l4 * 4 + r;
          int col  = wm * 32 + fm * 16 + l15;
          float vv = acc[fm][fn][r] + bias[n0 + drow];
          out[((size_t)(bidx * 8 + head) * 64 + drow) * 2048 + (m0 & 2047) + col] = f2bf(vv);
        }
  } else {
#pragma unroll
    for (int fm = 0; fm < 2; fm++)
#pragma unroll
      for (int fn = 0; fn < 2; fn++)
#pragma unroll
        for (int r = 0; r < 4; r++) {
          int row = wm * 32 + fm * 16 + l4 * 4 + r;
          int col = wn * 32 + fn * 16 + l15;
          int nrow = (m0 & 2047) + row;
          float vv = acc[fm][fn][r] + bias[n0 + col];
          out[(((size_t)(bidx * 8 + head) * 2048) + nrow) * 64 + col] = f2bf(vv);
        }
  }
}

// ---------------- flash attention ----------------
// round-2 barrier semantics (single buffer, barrier-write-barrier-compute);
// latency hiding via register prefetch: loads for tile t+1 issued right after
// the staging barrier of tile t, consumed at top of tile t+1.
__global__ __launch_bounds__(512, 4) void attn_kernel(
    const u16* __restrict__ Q, const u16* __restrict__ K, const u16* __restrict__ Vt,
    const float* __restrict__ bias, u16* __restrict__ O) {
  __shared__ u16 Klds[64 * LDSS];
  __shared__ u16 Vtlds[64 * LDSS];

  int qt = blockIdx.x, h = blockIdx.y, b = blockIdx.z;
  int tid = threadIdx.x;
  int lane = tid & 63, w = tid >> 6;
  int l15 = lane & 15, l4 = lane >> 4;
  int qrow = qt * 128 + w * 16 + l15;

  const u16* Qbh  = Q  + (size_t)(b * 8 + h) * 2048 * 64;
  const u16* Kbh  = K  + (size_t)(b * 8 + h) * 2048 * 64;
  const u16* Vtbh = Vt + (size_t)(b * 8 + h) * 64 * 2048;
  const float* biasrow = bias + (size_t)b * 2048 * 2048 + (size_t)qrow * 2048;

  bf16x8 aq[2];
#pragma unroll
  for (int kk = 0; kk < 2; kk++)
    aq[kk] = *(const bf16x8*)&Qbh[qrow * 64 + kk * 32 + l4 * 8];

  f32x4 o[4] = {};
  float mrow = -1e30f, lrow = 0.f;

  int srcA = (lane & 16) * 2 + l15;
  bool hiF = (l4 >> 1) != 0;

  int srow = tid >> 3, sc8 = (tid & 7) * 8;   // staging coords: 512 thr = full tile

  // prologue: prefetch tile 0 into registers
  uint4 kr = *(const uint4*)&Kbh[srow * 64 + sc8];
  uint4 vr = *(const uint4*)&Vtbh[srow * 2048 + sc8];
  float4 bb[4];
#pragma unroll
  for (int fj = 0; fj < 4; fj++)
    bb[fj] = *(const float4*)&biasrow[fj * 16 + l4 * 4];

  for (int t = 0; t < 32; t++) {
    __syncthreads();   // (A) previous compute done; LDS safe to overwrite
    *(uint4*)&Klds[srow * LDSS + sc8]  = kr;
    *(uint4*)&Vtlds[srow * LDSS + sc8] = vr;
    __syncthreads();   // (B) staging visible to all waves

    bool pf = (t < 31);
    float4 nbb[4];
    if (pf) {
      // issue next tile's loads NOW; they retire during this tile's compute
      kr = *(const uint4*)&Kbh[((t + 1) * 64 + srow) * 64 + sc8];
      vr = *(const uint4*)&Vtbh[srow * 2048 + (t + 1) * 64 + sc8];
#pragma unroll
      for (int fj = 0; fj < 4; fj++)
        nbb[fj] = *(const float4*)&biasrow[(t + 1) * 64 + fj * 16 + l4 * 4];
    }

    // S^T = K·Q^T : lane holds S[q=l15][k = fj*16 + l4*4 + r]
    f32x4 s[4] = {};
#pragma unroll
    for (int kk = 0; kk < 2; kk++)
#pragma unroll
      for (int fj = 0; fj < 4; fj++) {
        bf16x8 kf = *(const bf16x8*)&Klds[(fj * 16 + l15) * LDSS + kk * 32 + l4 * 8];
        s[fj] = __builtin_amdgcn_mfma_f32_16x16x32_bf16(kf, aq[kk], s[fj], 0, 0, 0);
      }

    // scale + bias (registers prefetched last iteration)
    float m = -1e30f;
#pragma unroll
    for (int fj = 0; fj < 4; fj++)
#pragma unroll
      for (int r = 0; r < 4; r++) {
        s[fj][r] = s[fj][r] * 0.125f + ((const float*)&bb[fj])[r];
        m = fmaxf(m, s[fj][r]);
      }
    m = fmaxf(m, __shfl_xor(m, 16));
    m = fmaxf(m, __shfl_xor(m, 32));
    float mnew = fmaxf(mrow, m);
    float corr = __expf(mrow - mnew);
    mrow = mnew;

    u32 pk[4][2];
    float sum = 0.f;
#pragma unroll
    for (int fj = 0; fj < 4; fj++) {
      float p0 = __expf(s[fj][0] - mnew);
      float p1 = __expf(s[fj][1] - mnew);
      float p2 = __expf(s[fj][2] - mnew);
      float p3 = __expf(s[fj][3] - mnew);
      sum += (p0 + p1) + (p2 + p3);
      pk[fj][0] = cvt_pk_bf16(p0, p1);
      pk[fj][1] = cvt_pk_bf16(p2, p3);
    }
    sum += __shfl_xor(sum, 16);
    sum += __shfl_xor(sum, 32);
    lrow = lrow * corr + sum;
#pragma unroll
    for (int fo = 0; fo < 4; fo++)
#pragma unroll
      for (int r = 0; r < 4; r++) o[fo][r] *= corr;

    // redistribute P^T -> PV B-fragments fully in-register
#pragma unroll
    for (int kk = 0; kk < 2; kk++) {
      u32 a0 = __shfl((int)pk[2 * kk][0],     srcA);
      u32 b0 = __shfl((int)pk[2 * kk + 1][0], srcA);
      u32 a1 = __shfl((int)pk[2 * kk][1],     srcA);
      u32 b1 = __shfl((int)pk[2 * kk + 1][1], srcA);
      u32 a2 = __shfl((int)pk[2 * kk][0],     srcA + 16);
      u32 b2 = __shfl((int)pk[2 * kk + 1][0], srcA + 16);
      u32 a3 = __shfl((int)pk[2 * kk][1],     srcA + 16);
      u32 b3 = __shfl((int)pk[2 * kk + 1][1], srcA + 16);
      union { u32 u[4]; bf16x8 v; } pu;
      pu.u[0] = hiF ? b0 : a0;
      pu.u[1] = hiF ? b1 : a1;
      pu.u[2] = hiF ? b2 : a2;
      pu.u[3] = hiF ? b3 : a3;
#pragma unroll
      for (int fo = 0; fo < 4; fo++) {
        bf16x8 vt = *(const bf16x8*)&Vtlds[(fo * 16 + l15) * LDSS + kk * 32 + l4 * 8];
        o[fo] = __builtin_amdgcn_mfma_f32_16x16x32_bf16(vt, pu.v, o[fo], 0, 0, 0);
      }
    }

    if (pf) {
#pragma unroll
      for (int fj = 0; fj < 4; fj++) bb[fj] = nbb[fj];
    }
  }

  // normalize + write O (b, n, h*64+d) bf16
  float inv = 1.0f / lrow;
  size_t obase = (size_t)(b * 2048 + qrow) * 512 + h * 64;
#pragma unroll
  for (int fo = 0; fo < 4; fo++) {
    u32 wlo = cvt_pk_bf16(o[fo][0] * inv, o[fo][1] * inv);
    u32 whi = cvt_pk_bf16(o[fo][2] * inv, o[fo][3] * inv);
    *(u32*)&O[obase + fo * 16 + l4 * 4]     = wlo;
    *(u32*)&O[obase + fo * 16 + l4 * 4 + 2] = whi;
  }
}

// ---------------- output projection ----------------
__global__ __launch_bounds__(256) void outproj_kernel(
    const u16* __restrict__ Ob, const u16* __restrict__ woT,
    const float* __restrict__ bo, float* __restrict__ out) {
  __shared__ u16 Alds[64 * LDSS];
  __shared__ u16 Blds[64 * LDSS];
  int m0 = blockIdx.y * 64;
  int n0 = blockIdx.x * 64;
  int tid = threadIdx.x;
  int lane = tid & 63, w = tid >> 6;
  int wm = w >> 1, wn = w & 1;
  int l15 = lane & 15, l4 = lane >> 4;

  f32x4 acc[2][2] = {};
  for (int k0 = 0; k0 < 512; k0 += 64) {
    __syncthreads();
#pragma unroll
    for (int c = tid; c < 512; c += 256) {
      int row = c >> 3, c8 = (c & 7) * 8;
      *(uint4*)&Alds[row * LDSS + c8] = *(const uint4*)&Ob[(m0 + row) * 512 + k0 + c8];
      *(uint4*)&Blds[row * LDSS + c8] = *(const uint4*)&woT[(n0 + row) * 512 + k0 + c8];
    }
    __syncthreads();
#pragma unroll
    for (int kk = 0; kk < 2; kk++) {
      bf16x8 a[2], bfr[2];
#pragma unroll
      for (int f = 0; f < 2; f++) {
        a[f] = *(const bf16x8*)&Alds[(wm * 32 + f * 16 + l15) * LDSS + kk * 32 + l4 * 8];
        bfr[f] = *(const bf16x8*)&Blds[(wn * 32 + f * 16 + l15) * LDSS + kk * 32 + l4 * 8];
      }
#pragma unroll
      for (int fm = 0; fm < 2; fm++)
#pragma unroll
        for (int fn = 0; fn < 2; fn++)
          acc[fm][fn] = __builtin_amdgcn_mfma_f32_16x16x32_bf16(a[fm], bfr[fn], acc[fm][fn], 0, 0, 0);
    }
  }
#pragma unroll
  for (int fm = 0; fm < 2; fm++)
#pragma unroll
    for (int fn = 0; fn < 2; fn++)
#pragma unroll
      for (int r = 0; r < 4; r++) {
        int row = wm * 32 + fm * 16 + l4 * 4 + r;
        int col = wn * 32 + fn * 16 + l15;
        out[(size_t)(m0 + row) * 512 + n0 + col] = acc[fm][fn][r] + bo[n0 + col];
      }
}

extern "C" void kernel_launch(void* const* d_in, const int* in_sizes, int n_in,
                              void* d_out, int out_size, void* d_ws, size_t ws_size,
                              hipStream_t stream) {
  const float* x    = (const float*)d_in[0];
  const float* bias = (const float*)d_in[1];
  const float* wq   = (const float*)d_in[2];
  const float* bq   = (const float*)d_in[3];
  const float* wk   = (const float*)d_in[4];
  const float* bk   = (const float*)d_in[5];
  const float* wv   = (const float*)d_in[6];
  const float* bv   = (const float*)d_in[7];
  const float* wo   = (const float*)d_in[8];
  const float* bo   = (const float*)d_in[9];
  float* out = (float*)d_out;

  char* ws = (char*)d_ws;
  u16* xb  = (u16*)(ws + 0);
  u16* wqT = (u16*)(ws + 8388608);
  u16* wkT = (u16*)(ws + 8912896);
  u16* wvT = (u16*)(ws + 9437184);
  u16* woT = (u16*)(ws + 9961472);
  u16* Qb  = (u16*)(ws + 10485760);
  u16* Kb  = (u16*)(ws + 18874368);
  u16* VtB = (u16*)(ws + 27262976);
  u16* Ob  = (u16*)(ws + 35651584);

  hipLaunchKernelGGL(cast_x_kernel, dim3(2048), dim3(256), 0, stream, x, xb);
  hipLaunchKernelGGL(cast_wT_kernel, dim3(4096), dim3(256), 0, stream,
                     wq, wk, wv, wo, wqT, wkT, wvT, woT);
  hipLaunchKernelGGL(proj_kernel, dim3(8, 128, 3), dim3(256), 0, stream,
                     xb, wqT, wkT, wvT, bq, bk, bv, Qb, Kb, VtB);
  hipLaunchKernelGGL(attn_kernel, dim3(16, 8, 4), dim3(512), 0, stream,
                     Qb, Kb, VtB, bias, Ob);
  hipLaunchKernelGGL(outproj_kernel, dim3(8, 128), dim3(256), 0, stream,
                     Ob, woT, bo, out);
}

// Round 5
// 149.336 us; speedup vs baseline: 1.5486x; 1.0331x over previous
//
#include <hip/hip_runtime.h>
#include <hip/hip_bf16.h>

typedef __bf16 bf16x8 __attribute__((ext_vector_type(8)));
typedef float f32x4 __attribute__((ext_vector_type(4)));
using u16 = unsigned short;
using u32 = unsigned int;

#define LDSS 72  // padded LDS row stride in bf16 elems (2-way b128 floor)

__device__ __forceinline__ u16 f2bf(float f) {
  union { float f; u32 u; } v; v.f = f;
  u32 r = v.u + 0x7fffu + ((v.u >> 16) & 1u);   // RNE
  return (u16)(r >> 16);
}

__device__ __forceinline__ u32 cvt_pk_bf16(float lo, float hi) {
  u32 r;
  asm("v_cvt_pk_bf16_f32 %0, %1, %2" : "=v"(r) : "v"(lo), "v"(hi));
  return r;
}

// ---------------- cast kernels ----------------
__global__ void cast_x_kernel(const float* __restrict__ x, u16* __restrict__ xb) {
  int i = (blockIdx.x * 256 + threadIdx.x) * 8;
  float4 f0 = *(const float4*)&x[i];
  float4 f1 = *(const float4*)&x[i + 4];
  u16 u[8];
  u[0] = f2bf(f0.x); u[1] = f2bf(f0.y); u[2] = f2bf(f0.z); u[3] = f2bf(f0.w);
  u[4] = f2bf(f1.x); u[5] = f2bf(f1.y); u[6] = f2bf(f1.z); u[7] = f2bf(f1.w);
  *(uint4*)&xb[i] = *(uint4*)u;
}

// weights (512x512, stored in,out) -> bf16 transposed (out,in)
__global__ void cast_wT_kernel(const float* __restrict__ w0, const float* __restrict__ w1,
                               const float* __restrict__ w2, const float* __restrict__ w3,
                               u16* __restrict__ t0, u16* __restrict__ t1,
                               u16* __restrict__ t2, u16* __restrict__ t3) {
  int i = blockIdx.x * 256 + threadIdx.x;
  int wi = i >> 18;
  int r = i & 262143;
  int row = r >> 9, col = r & 511;
  const float* w; u16* t;
  if (wi == 0)      { w = w0; t = t0; }
  else if (wi == 1) { w = w1; t = t1; }
  else if (wi == 2) { w = w2; t = t2; }
  else              { w = w3; t = t3; }
  t[col * 512 + row] = f2bf(w[r]);
}

// ---------------- QKV projection GEMM (reg-prefetch pipelined) ----------------
__global__ __launch_bounds__(256) void proj_kernel(
    const u16* __restrict__ xb,
    const u16* __restrict__ wqT, const u16* __restrict__ wkT, const u16* __restrict__ wvT,
    const float* __restrict__ bq, const float* __restrict__ bk, const float* __restrict__ bv,
    u16* __restrict__ Q, u16* __restrict__ K, u16* __restrict__ Vt) {
  __shared__ u16 Alds[64 * LDSS];
  __shared__ u16 Blds[64 * LDSS];
  int which = blockIdx.z;
  const u16* wT; const float* bias; u16* out;
  if (which == 0)      { wT = wqT; bias = bq; out = Q; }
  else if (which == 1) { wT = wkT; bias = bk; out = K; }
  else                 { wT = wvT; bias = bv; out = Vt; }

  int m0 = blockIdx.y * 64;
  int n0 = blockIdx.x * 64;
  int tid = threadIdx.x;
  int lane = tid & 63, w = tid >> 6;
  int wm = w >> 1, wn = w & 1;
  int l15 = lane & 15, l4 = lane >> 4;

  // staging chunk coords: chunks c=tid and c=tid+256 of 512; row=c>>3, col=(c&7)*8
  int r0 = tid >> 3, c8 = (tid & 7) * 8;

  // prologue: prefetch k0=0
  uint4 ar0 = *(const uint4*)&xb[(m0 + r0) * 512 + c8];
  uint4 ar1 = *(const uint4*)&xb[(m0 + r0 + 32) * 512 + c8];
  uint4 br0 = *(const uint4*)&wT[(n0 + r0) * 512 + c8];
  uint4 br1 = *(const uint4*)&wT[(n0 + r0 + 32) * 512 + c8];

  f32x4 acc[2][2] = {};
  for (int ks = 0; ks < 8; ks++) {
    __syncthreads();
    *(uint4*)&Alds[r0 * LDSS + c8]        = ar0;
    *(uint4*)&Alds[(r0 + 32) * LDSS + c8] = ar1;
    *(uint4*)&Blds[r0 * LDSS + c8]        = br0;
    *(uint4*)&Blds[(r0 + 32) * LDSS + c8] = br1;
    __syncthreads();
    if (ks < 7) {
      int k0 = (ks + 1) * 64;
      ar0 = *(const uint4*)&xb[(m0 + r0) * 512 + k0 + c8];
      ar1 = *(const uint4*)&xb[(m0 + r0 + 32) * 512 + k0 + c8];
      br0 = *(const uint4*)&wT[(n0 + r0) * 512 + k0 + c8];
      br1 = *(const uint4*)&wT[(n0 + r0 + 32) * 512 + k0 + c8];
    }
#pragma unroll
    for (int kk = 0; kk < 2; kk++) {
      bf16x8 a[2], b[2];
#pragma unroll
      for (int f = 0; f < 2; f++) {
        a[f] = *(const bf16x8*)&Alds[(wm * 32 + f * 16 + l15) * LDSS + kk * 32 + l4 * 8];
        b[f] = *(const bf16x8*)&Blds[(wn * 32 + f * 16 + l15) * LDSS + kk * 32 + l4 * 8];
      }
#pragma unroll
      for (int fm = 0; fm < 2; fm++)
#pragma unroll
        for (int fn = 0; fn < 2; fn++) {
          if (which == 2)
            acc[fm][fn] = __builtin_amdgcn_mfma_f32_16x16x32_bf16(b[fn], a[fm], acc[fm][fn], 0, 0, 0);
          else
            acc[fm][fn] = __builtin_amdgcn_mfma_f32_16x16x32_bf16(a[fm], b[fn], acc[fm][fn], 0, 0, 0);
        }
    }
  }
  int bidx = m0 >> 11;
  int head = n0 >> 6;
  if (which == 2) {
#pragma unroll
    for (int fm = 0; fm < 2; fm++)
#pragma unroll
      for (int fn = 0; fn < 2; fn++)
#pragma unroll
        for (int r = 0; r < 4; r++) {
          int drow = wn * 32 + fn * 16 + l4 * 4 + r;
          int col  = wm * 32 + fm * 16 + l15;
          float vv = acc[fm][fn][r] + bias[n0 + drow];
          out[((size_t)(bidx * 8 + head) * 64 + drow) * 2048 + (m0 & 2047) + col] = f2bf(vv);
        }
  } else {
#pragma unroll
    for (int fm = 0; fm < 2; fm++)
#pragma unroll
      for (int fn = 0; fn < 2; fn++)
#pragma unroll
        for (int r = 0; r < 4; r++) {
          int row = wm * 32 + fm * 16 + l4 * 4 + r;
          int col = wn * 32 + fn * 16 + l15;
          int nrow = (m0 & 2047) + row;
          float vv = acc[fm][fn][r] + bias[n0 + col];
          out[(((size_t)(bidx * 8 + head) * 2048) + nrow) * 64 + col] = f2bf(vv);
        }
  }
}

// ---------------- flash attention ----------------
// 4 waves/block, qtile=64, grid 1024 (4 blocks/CU = 4 barrier groups);
// round-2 barrier semantics + reg prefetch; defer-max; setprio on MFMA.
__global__ __launch_bounds__(256, 4) void attn_kernel(
    const u16* __restrict__ Q, const u16* __restrict__ K, const u16* __restrict__ Vt,
    const float* __restrict__ bias, u16* __restrict__ O) {
  __shared__ u16 Klds[64 * LDSS];
  __shared__ u16 Vtlds[64 * LDSS];

  int qt = blockIdx.x, h = blockIdx.y, b = blockIdx.z;
  int tid = threadIdx.x;
  int lane = tid & 63, w = tid >> 6;
  int l15 = lane & 15, l4 = lane >> 4;
  int qrow = qt * 64 + w * 16 + l15;

  const u16* Qbh  = Q  + (size_t)(b * 8 + h) * 2048 * 64;
  const u16* Kbh  = K  + (size_t)(b * 8 + h) * 2048 * 64;
  const u16* Vtbh = Vt + (size_t)(b * 8 + h) * 64 * 2048;
  const float* biasrow = bias + (size_t)b * 2048 * 2048 + (size_t)qrow * 2048;

  bf16x8 aq[2];
#pragma unroll
  for (int kk = 0; kk < 2; kk++)
    aq[kk] = *(const bf16x8*)&Qbh[qrow * 64 + kk * 32 + l4 * 8];

  f32x4 o[4] = {};
  float mrow = -1e30f, lrow = 0.f;

  int srcA = (lane & 16) * 2 + l15;
  bool hiF = (l4 >> 1) != 0;

  // staging: chunks c=tid, c=tid+256 of 512; row=c>>3 (0..31 / 32..63), col=(tid&7)*8
  int r0 = tid >> 3, c8 = (tid & 7) * 8;

  // prologue: prefetch tile 0 into registers
  uint4 kr0 = *(const uint4*)&Kbh[r0 * 64 + c8];
  uint4 kr1 = *(const uint4*)&Kbh[(32 + r0) * 64 + c8];
  uint4 vr0 = *(const uint4*)&Vtbh[r0 * 2048 + c8];
  uint4 vr1 = *(const uint4*)&Vtbh[(r0 + 32) * 2048 + c8];
  float4 bb[4];
#pragma unroll
  for (int fj = 0; fj < 4; fj++)
    bb[fj] = *(const float4*)&biasrow[fj * 16 + l4 * 4];

  for (int t = 0; t < 32; t++) {
    __syncthreads();   // (A) previous compute done; LDS safe to overwrite
    *(uint4*)&Klds[r0 * LDSS + c8]         = kr0;
    *(uint4*)&Klds[(r0 + 32) * LDSS + c8]  = kr1;
    *(uint4*)&Vtlds[r0 * LDSS + c8]        = vr0;
    *(uint4*)&Vtlds[(r0 + 32) * LDSS + c8] = vr1;
    __syncthreads();   // (B) staging visible

    bool pf = (t < 31);
    float4 nbb[4];
    if (pf) {
      kr0 = *(const uint4*)&Kbh[((t + 1) * 64 + r0) * 64 + c8];
      kr1 = *(const uint4*)&Kbh[((t + 1) * 64 + 32 + r0) * 64 + c8];
      vr0 = *(const uint4*)&Vtbh[r0 * 2048 + (t + 1) * 64 + c8];
      vr1 = *(const uint4*)&Vtbh[(r0 + 32) * 2048 + (t + 1) * 64 + c8];
#pragma unroll
      for (int fj = 0; fj < 4; fj++)
        nbb[fj] = *(const float4*)&biasrow[(t + 1) * 64 + fj * 16 + l4 * 4];
    }

    // S^T = K·Q^T
    f32x4 s[4] = {};
    __builtin_amdgcn_s_setprio(1);
#pragma unroll
    for (int kk = 0; kk < 2; kk++)
#pragma unroll
      for (int fj = 0; fj < 4; fj++) {
        bf16x8 kf = *(const bf16x8*)&Klds[(fj * 16 + l15) * LDSS + kk * 32 + l4 * 8];
        s[fj] = __builtin_amdgcn_mfma_f32_16x16x32_bf16(kf, aq[kk], s[fj], 0, 0, 0);
      }
    __builtin_amdgcn_s_setprio(0);

    // scale + bias
    float m = -1e30f;
#pragma unroll
    for (int fj = 0; fj < 4; fj++)
#pragma unroll
      for (int r = 0; r < 4; r++) {
        s[fj][r] = s[fj][r] * 0.125f + ((const float*)&bb[fj])[r];
        m = fmaxf(m, s[fj][r]);
      }
    m = fmaxf(m, __shfl_xor(m, 16));
    m = fmaxf(m, __shfl_xor(m, 32));

    // defer-max (T13): rescale only when tile max exceeds running max by >8
    if (!__all(m <= mrow + 8.0f)) {
      float mnew = fmaxf(mrow, m);
      float corr = __expf(mrow - mnew);
      mrow = mnew;
      lrow *= corr;
#pragma unroll
      for (int fo = 0; fo < 4; fo++)
#pragma unroll
        for (int r = 0; r < 4; r++) o[fo][r] *= corr;
    }

    u32 pk[4][2];
    float sum = 0.f;
#pragma unroll
    for (int fj = 0; fj < 4; fj++) {
      float p0 = __expf(s[fj][0] - mrow);
      float p1 = __expf(s[fj][1] - mrow);
      float p2 = __expf(s[fj][2] - mrow);
      float p3 = __expf(s[fj][3] - mrow);
      sum += (p0 + p1) + (p2 + p3);
      pk[fj][0] = cvt_pk_bf16(p0, p1);
      pk[fj][1] = cvt_pk_bf16(p2, p3);
    }
    sum += __shfl_xor(sum, 16);
    sum += __shfl_xor(sum, 32);
    lrow += sum;

    // redistribute P^T -> PV B-fragments in-register
#pragma unroll
    for (int kk = 0; kk < 2; kk++) {
      u32 a0 = __shfl((int)pk[2 * kk][0],     srcA);
      u32 b0 = __shfl((int)pk[2 * kk + 1][0], srcA);
      u32 a1 = __shfl((int)pk[2 * kk][1],     srcA);
      u32 b1 = __shfl((int)pk[2 * kk + 1][1], srcA);
      u32 a2 = __shfl((int)pk[2 * kk][0],     srcA + 16);
      u32 b2 = __shfl((int)pk[2 * kk + 1][0], srcA + 16);
      u32 a3 = __shfl((int)pk[2 * kk][1],     srcA + 16);
      u32 b3 = __shfl((int)pk[2 * kk + 1][1], srcA + 16);
      union { u32 u[4]; bf16x8 v; } pu;
      pu.u[0] = hiF ? b0 : a0;
      pu.u[1] = hiF ? b1 : a1;
      pu.u[2] = hiF ? b2 : a2;
      pu.u[3] = hiF ? b3 : a3;
      __builtin_amdgcn_s_setprio(1);
#pragma unroll
      for (int fo = 0; fo < 4; fo++) {
        bf16x8 vt = *(const bf16x8*)&Vtlds[(fo * 16 + l15) * LDSS + kk * 32 + l4 * 8];
        o[fo] = __builtin_amdgcn_mfma_f32_16x16x32_bf16(vt, pu.v, o[fo], 0, 0, 0);
      }
      __builtin_amdgcn_s_setprio(0);
    }

    if (pf) {
#pragma unroll
      for (int fj = 0; fj < 4; fj++) bb[fj] = nbb[fj];
    }
  }

  // normalize + write O (b, n, h*64+d) bf16
  float inv = 1.0f / lrow;
  size_t obase = (size_t)(b * 2048 + qrow) * 512 + h * 64;
#pragma unroll
  for (int fo = 0; fo < 4; fo++) {
    u32 wlo = cvt_pk_bf16(o[fo][0] * inv, o[fo][1] * inv);
    u32 whi = cvt_pk_bf16(o[fo][2] * inv, o[fo][3] * inv);
    *(u32*)&O[obase + fo * 16 + l4 * 4]     = wlo;
    *(u32*)&O[obase + fo * 16 + l4 * 4 + 2] = whi;
  }
}

// ---------------- output projection (reg-prefetch pipelined) ----------------
__global__ __launch_bounds__(256) void outproj_kernel(
    const u16* __restrict__ Ob, const u16* __restrict__ woT,
    const float* __restrict__ bo, float* __restrict__ out) {
  __shared__ u16 Alds[64 * LDSS];
  __shared__ u16 Blds[64 * LDSS];
  int m0 = blockIdx.y * 64;
  int n0 = blockIdx.x * 64;
  int tid = threadIdx.x;
  int lane = tid & 63, w = tid >> 6;
  int wm = w >> 1, wn = w & 1;
  int l15 = lane & 15, l4 = lane >> 4;

  int r0 = tid >> 3, c8 = (tid & 7) * 8;
  uint4 ar0 = *(const uint4*)&Ob[(m0 + r0) * 512 + c8];
  uint4 ar1 = *(const uint4*)&Ob[(m0 + r0 + 32) * 512 + c8];
  uint4 br0 = *(const uint4*)&woT[(n0 + r0) * 512 + c8];
  uint4 br1 = *(const uint4*)&woT[(n0 + r0 + 32) * 512 + c8];

  f32x4 acc[2][2] = {};
  for (int ks = 0; ks < 8; ks++) {
    __syncthreads();
    *(uint4*)&Alds[r0 * LDSS + c8]        = ar0;
    *(uint4*)&Alds[(r0 + 32) * LDSS + c8] = ar1;
    *(uint4*)&Blds[r0 * LDSS + c8]        = br0;
    *(uint4*)&Blds[(r0 + 32) * LDSS + c8] = br1;
    __syncthreads();
    if (ks < 7) {
      int k0 = (ks + 1) * 64;
      ar0 = *(const uint4*)&Ob[(m0 + r0) * 512 + k0 + c8];
      ar1 = *(const uint4*)&Ob[(m0 + r0 + 32) * 512 + k0 + c8];
      br0 = *(const uint4*)&woT[(n0 + r0) * 512 + k0 + c8];
      br1 = *(const uint4*)&woT[(n0 + r0 + 32) * 512 + k0 + c8];
    }
#pragma unroll
    for (int kk = 0; kk < 2; kk++) {
      bf16x8 a[2], bfr[2];
#pragma unroll
      for (int f = 0; f < 2; f++) {
        a[f] = *(const bf16x8*)&Alds[(wm * 32 + f * 16 + l15) * LDSS + kk * 32 + l4 * 8];
        bfr[f] = *(const bf16x8*)&Blds[(wn * 32 + f * 16 + l15) * LDSS + kk * 32 + l4 * 8];
      }
#pragma unroll
      for (int fm = 0; fm < 2; fm++)
#pragma unroll
        for (int fn = 0; fn < 2; fn++)
          acc[fm][fn] = __builtin_amdgcn_mfma_f32_16x16x32_bf16(a[fm], bfr[fn], acc[fm][fn], 0, 0, 0);
    }
  }
#pragma unroll
  for (int fm = 0; fm < 2; fm++)
#pragma unroll
    for (int fn = 0; fn < 2; fn++)
#pragma unroll
      for (int r = 0; r < 4; r++) {
        int row = wm * 32 + fm * 16 + l4 * 4 + r;
        int col = wn * 32 + fn * 16 + l15;
        out[(size_t)(m0 + row) * 512 + n0 + col] = acc[fm][fn][r] + bo[n0 + col];
      }
}

extern "C" void kernel_launch(void* const* d_in, const int* in_sizes, int n_in,
                              void* d_out, int out_size, void* d_ws, size_t ws_size,
                              hipStream_t stream) {
  const float* x    = (const float*)d_in[0];
  const float* bias = (const float*)d_in[1];
  const float* wq   = (const float*)d_in[2];
  const float* bq   = (const float*)d_in[3];
  const float* wk   = (const float*)d_in[4];
  const float* bk   = (const float*)d_in[5];
  const float* wv   = (const float*)d_in[6];
  const float* bv   = (const float*)d_in[7];
  const float* wo   = (const float*)d_in[8];
  const float* bo   = (const float*)d_in[9];
  float* out = (float*)d_out;

  char* ws = (char*)d_ws;
  u16* xb  = (u16*)(ws + 0);
  u16* wqT = (u16*)(ws + 8388608);
  u16* wkT = (u16*)(ws + 8912896);
  u16* wvT = (u16*)(ws + 9437184);
  u16* woT = (u16*)(ws + 9961472);
  u16* Qb  = (u16*)(ws + 10485760);
  u16* Kb  = (u16*)(ws + 18874368);
  u16* VtB = (u16*)(ws + 27262976);
  u16* Ob  = (u16*)(ws + 35651584);

  hipLaunchKernelGGL(cast_x_kernel, dim3(2048), dim3(256), 0, stream, x, xb);
  hipLaunchKernelGGL(cast_wT_kernel, dim3(4096), dim3(256), 0, stream,
                     wq, wk, wv, wo, wqT, wkT, wvT, woT);
  hipLaunchKernelGGL(proj_kernel, dim3(8, 128, 3), dim3(256), 0, stream,
                     xb, wqT, wkT, wvT, bq, bk, bv, Qb, Kb, VtB);
  hipLaunchKernelGGL(attn_kernel, dim3(32, 8, 4), dim3(256), 0, stream,
                     Qb, Kb, VtB, bias, Ob);
  hipLaunchKernelGGL(outproj_kernel, dim3(8, 128), dim3(256), 0, stream,
                     Ob, woT, bo, out);
}

// Round 6
// 139.751 us; speedup vs baseline: 1.6548x; 1.0686x over previous
//
#include <hip/hip_runtime.h>
#include <hip/hip_bf16.h>

typedef __bf16 bf16x8 __attribute__((ext_vector_type(8)));
typedef float f32x4 __attribute__((ext_vector_type(4)));
typedef float f32x16 __attribute__((ext_vector_type(16)));
using u16 = unsigned short;
using u32 = unsigned int;

#define LDSS 72  // padded LDS row stride in bf16 elems

__device__ __forceinline__ u16 f2bf(float f) {
  union { float f; u32 u; } v; v.f = f;
  u32 r = v.u + 0x7fffu + ((v.u >> 16) & 1u);   // RNE
  return (u16)(r >> 16);
}

__device__ __forceinline__ u32 cvt_pk_bf16(float lo, float hi) {
  u32 r;
  asm("v_cvt_pk_bf16_f32 %0, %1, %2" : "=v"(r) : "v"(lo), "v"(hi));
  return r;
}

// ---------------- cast kernels ----------------
__global__ void cast_x_kernel(const float* __restrict__ x, u16* __restrict__ xb) {
  int i = (blockIdx.x * 256 + threadIdx.x) * 8;
  float4 f0 = *(const float4*)&x[i];
  float4 f1 = *(const float4*)&x[i + 4];
  u16 u[8];
  u[0] = f2bf(f0.x); u[1] = f2bf(f0.y); u[2] = f2bf(f0.z); u[3] = f2bf(f0.w);
  u[4] = f2bf(f1.x); u[5] = f2bf(f1.y); u[6] = f2bf(f1.z); u[7] = f2bf(f1.w);
  *(uint4*)&xb[i] = *(uint4*)u;
}

// weights (512x512, stored in,out) -> bf16 transposed (out,in)
__global__ void cast_wT_kernel(const float* __restrict__ w0, const float* __restrict__ w1,
                               const float* __restrict__ w2, const float* __restrict__ w3,
                               u16* __restrict__ t0, u16* __restrict__ t1,
                               u16* __restrict__ t2, u16* __restrict__ t3) {
  int i = blockIdx.x * 256 + threadIdx.x;
  int wi = i >> 18;
  int r = i & 262143;
  int row = r >> 9, col = r & 511;
  const float* w; u16* t;
  if (wi == 0)      { w = w0; t = t0; }
  else if (wi == 1) { w = w1; t = t1; }
  else if (wi == 2) { w = w2; t = t2; }
  else              { w = w3; t = t3; }
  t[col * 512 + row] = f2bf(w[r]);
}

// ---------------- QKV projection GEMM (reg-prefetch pipelined) ----------------
__global__ __launch_bounds__(256) void proj_kernel(
    const u16* __restrict__ xb,
    const u16* __restrict__ wqT, const u16* __restrict__ wkT, const u16* __restrict__ wvT,
    const float* __restrict__ bq, const float* __restrict__ bk, const float* __restrict__ bv,
    u16* __restrict__ Q, u16* __restrict__ K, u16* __restrict__ Vt) {
  __shared__ u16 Alds[64 * LDSS];
  __shared__ u16 Blds[64 * LDSS];
  int which = blockIdx.z;
  const u16* wT; const float* bias; u16* out;
  if (which == 0)      { wT = wqT; bias = bq; out = Q; }
  else if (which == 1) { wT = wkT; bias = bk; out = K; }
  else                 { wT = wvT; bias = bv; out = Vt; }

  int m0 = blockIdx.y * 64;
  int n0 = blockIdx.x * 64;
  int tid = threadIdx.x;
  int lane = tid & 63, w = tid >> 6;
  int wm = w >> 1, wn = w & 1;
  int l15 = lane & 15, l4 = lane >> 4;

  int r0 = tid >> 3, c8 = (tid & 7) * 8;

  uint4 ar0 = *(const uint4*)&xb[(m0 + r0) * 512 + c8];
  uint4 ar1 = *(const uint4*)&xb[(m0 + r0 + 32) * 512 + c8];
  uint4 br0 = *(const uint4*)&wT[(n0 + r0) * 512 + c8];
  uint4 br1 = *(const uint4*)&wT[(n0 + r0 + 32) * 512 + c8];

  f32x4 acc[2][2] = {};
  for (int ks = 0; ks < 8; ks++) {
    __syncthreads();
    *(uint4*)&Alds[r0 * LDSS + c8]        = ar0;
    *(uint4*)&Alds[(r0 + 32) * LDSS + c8] = ar1;
    *(uint4*)&Blds[r0 * LDSS + c8]        = br0;
    *(uint4*)&Blds[(r0 + 32) * LDSS + c8] = br1;
    __syncthreads();
    if (ks < 7) {
      int k0 = (ks + 1) * 64;
      ar0 = *(const uint4*)&xb[(m0 + r0) * 512 + k0 + c8];
      ar1 = *(const uint4*)&xb[(m0 + r0 + 32) * 512 + k0 + c8];
      br0 = *(const uint4*)&wT[(n0 + r0) * 512 + k0 + c8];
      br1 = *(const uint4*)&wT[(n0 + r0 + 32) * 512 + k0 + c8];
    }
#pragma unroll
    for (int kk = 0; kk < 2; kk++) {
      bf16x8 a[2], b[2];
#pragma unroll
      for (int f = 0; f < 2; f++) {
        a[f] = *(const bf16x8*)&Alds[(wm * 32 + f * 16 + l15) * LDSS + kk * 32 + l4 * 8];
        b[f] = *(const bf16x8*)&Blds[(wn * 32 + f * 16 + l15) * LDSS + kk * 32 + l4 * 8];
      }
#pragma unroll
      for (int fm = 0; fm < 2; fm++)
#pragma unroll
        for (int fn = 0; fn < 2; fn++) {
          if (which == 2)
            acc[fm][fn] = __builtin_amdgcn_mfma_f32_16x16x32_bf16(b[fn], a[fm], acc[fm][fn], 0, 0, 0);
          else
            acc[fm][fn] = __builtin_amdgcn_mfma_f32_16x16x32_bf16(a[fm], b[fn], acc[fm][fn], 0, 0, 0);
        }
    }
  }
  int bidx = m0 >> 11;
  int head = n0 >> 6;
  if (which == 2) {
#pragma unroll
    for (int fm = 0; fm < 2; fm++)
#pragma unroll
      for (int fn = 0; fn < 2; fn++)
#pragma unroll
        for (int r = 0; r < 4; r++) {
          int drow = wn * 32 + fn * 16 + l4 * 4 + r;
          int col  = wm * 32 + fm * 16 + l15;
          float vv = acc[fm][fn][r] + bias[n0 + drow];
          out[((size_t)(bidx * 8 + head) * 64 + drow) * 2048 + (m0 & 2047) + col] = f2bf(vv);
        }
  } else {
#pragma unroll
    for (int fm = 0; fm < 2; fm++)
#pragma unroll
      for (int fn = 0; fn < 2; fn++)
#pragma unroll
        for (int r = 0; r < 4; r++) {
          int row = wm * 32 + fm * 16 + l4 * 4 + r;
          int col = wn * 32 + fn * 16 + l15;
          int nrow = (m0 & 2047) + row;
          float vv = acc[fm][fn][r] + bias[n0 + col];
          out[(((size_t)(bidx * 8 + head) * 2048) + nrow) * 64 + col] = f2bf(vv);
        }
  }
}

// ---------------- flash attention: 32x32 MFMA, swapped QK^T ----------------
// 4 waves x 32 q-rows = qtile 128; KV tile 64; grid 512.
// Lane (q=l&31, hi=l>>5) holds S row halves: S[k=kt*32+(reg&3)+8*(reg>>2)+4*hi][q].
__global__ __launch_bounds__(256, 2) void attn_kernel(
    const u16* __restrict__ Q, const u16* __restrict__ K, const u16* __restrict__ Vt,
    const float* __restrict__ bias, u16* __restrict__ O) {
  __shared__ u16 Klds[64 * LDSS];
  __shared__ u16 Vtlds[64 * LDSS];

  int qt = blockIdx.x, h = blockIdx.y, b = blockIdx.z;
  int tid = threadIdx.x;
  int lane = tid & 63, w = tid >> 6;
  int l31 = lane & 31, hi = lane >> 5;
  int qrow = qt * 128 + w * 32 + l31;

  const u16* Qbh  = Q  + (size_t)(b * 8 + h) * 2048 * 64;
  const u16* Kbh  = K  + (size_t)(b * 8 + h) * 2048 * 64;
  const u16* Vtbh = Vt + (size_t)(b * 8 + h) * 64 * 2048;
  const float* biasq = bias + (size_t)b * 2048 * 2048 + (size_t)qrow * 2048;

  // Q B-fragments: col=q (l31), k=d: dk*16 + hi*8
  bf16x8 qf[4];
#pragma unroll
  for (int dk = 0; dk < 4; dk++)
    qf[dk] = *(const bf16x8*)&Qbh[qrow * 64 + dk * 16 + hi * 8];

  f32x16 o[2] = {};
  float mrow = -1e30f, lrow = 0.f;

  int r0 = tid >> 3, c8 = (tid & 7) * 8;

  // prologue: prefetch tile 0 K/Vt + bias tile 0
  uint4 kr0 = *(const uint4*)&Kbh[r0 * 64 + c8];
  uint4 kr1 = *(const uint4*)&Kbh[(32 + r0) * 64 + c8];
  uint4 vr0 = *(const uint4*)&Vtbh[r0 * 2048 + c8];
  uint4 vr1 = *(const uint4*)&Vtbh[(r0 + 32) * 2048 + c8];
  float4 bb[8];
#pragma unroll
  for (int kt = 0; kt < 2; kt++)
#pragma unroll
    for (int g = 0; g < 4; g++)
      bb[kt * 4 + g] = *(const float4*)&biasq[kt * 32 + 8 * g + 4 * hi];

  for (int t = 0; t < 32; t++) {
    __syncthreads();   // (A) prev compute done
    *(uint4*)&Klds[r0 * LDSS + c8]         = kr0;
    *(uint4*)&Klds[(r0 + 32) * LDSS + c8]  = kr1;
    *(uint4*)&Vtlds[r0 * LDSS + c8]        = vr0;
    *(uint4*)&Vtlds[(r0 + 32) * LDSS + c8] = vr1;
    __syncthreads();   // (B) staging visible

    bool pf = (t < 31);
    if (pf) {
      kr0 = *(const uint4*)&Kbh[((t + 1) * 64 + r0) * 64 + c8];
      kr1 = *(const uint4*)&Kbh[((t + 1) * 64 + 32 + r0) * 64 + c8];
      vr0 = *(const uint4*)&Vtbh[r0 * 2048 + (t + 1) * 64 + c8];
      vr1 = *(const uint4*)&Vtbh[(r0 + 32) * 2048 + (t + 1) * 64 + c8];
    }

    // S^T = K·Q^T (two 32x32 k-tiles)
    f32x16 s[2] = {};
    __builtin_amdgcn_s_setprio(1);
#pragma unroll
    for (int dk = 0; dk < 4; dk++) {
      bf16x8 a0 = *(const bf16x8*)&Klds[l31 * LDSS + dk * 16 + hi * 8];
      s[0] = __builtin_amdgcn_mfma_f32_32x32x16_bf16(a0, qf[dk], s[0], 0, 0, 0);
      bf16x8 a1 = *(const bf16x8*)&Klds[(32 + l31) * LDSS + dk * 16 + hi * 8];
      s[1] = __builtin_amdgcn_mfma_f32_32x32x16_bf16(a1, qf[dk], s[1], 0, 0, 0);
    }
    __builtin_amdgcn_s_setprio(0);

    // scale + bias + in-lane max
    float m = -1e30f;
#pragma unroll
    for (int kt = 0; kt < 2; kt++)
#pragma unroll
      for (int g = 0; g < 4; g++) {
        float4 bv4 = bb[kt * 4 + g];
#pragma unroll
        for (int j = 0; j < 4; j++) {
          float val = s[kt][g * 4 + j] * 0.125f + ((const float*)&bv4)[j];
          s[kt][g * 4 + j] = val;
          m = fmaxf(m, val);
        }
      }
    m = fmaxf(m, __shfl_xor(m, 32));

    // defer-max (T13)
    if (!__all(m <= mrow + 8.0f)) {
      float mnew = fmaxf(mrow, m);
      float corr = __expf(mrow - mnew);
      mrow = mnew;
      lrow *= corr;
#pragma unroll
      for (int dt = 0; dt < 2; dt++)
#pragma unroll
        for (int i = 0; i < 16; i++) o[dt][i] *= corr;
    }

    // exp + pack
    u32 c[2][8];
    float sum = 0.f;
#pragma unroll
    for (int kt = 0; kt < 2; kt++)
#pragma unroll
      for (int g = 0; g < 4; g++) {
        float p0 = __expf(s[kt][g * 4 + 0] - mrow);
        float p1 = __expf(s[kt][g * 4 + 1] - mrow);
        float p2 = __expf(s[kt][g * 4 + 2] - mrow);
        float p3 = __expf(s[kt][g * 4 + 3] - mrow);
        sum += (p0 + p1) + (p2 + p3);
        c[kt][2 * g]     = cvt_pk_bf16(p0, p1);
        c[kt][2 * g + 1] = cvt_pk_bf16(p2, p3);
      }
    sum += __shfl_xor(sum, 32);
    lrow += sum;

    // exchange packed P words with partner lane (lane^32)
    u32 dx[2][8];
#pragma unroll
    for (int kt = 0; kt < 2; kt++)
#pragma unroll
      for (int j = 0; j < 8; j++)
        dx[kt][j] = (u32)__shfl_xor((int)c[kt][j], 32);

    // prefetch next tile's bias (bb consumed above)
    if (pf) {
#pragma unroll
      for (int kt = 0; kt < 2; kt++)
#pragma unroll
        for (int g = 0; g < 4; g++)
          bb[kt * 4 + g] = *(const float4*)&biasq[(t + 1) * 64 + kt * 32 + 8 * g + 4 * hi];
    }

    // build P^T B-frags + PV: O^T[d][q] += Vt[d][k]·P^T[k][q]
    __builtin_amdgcn_s_setprio(1);
#pragma unroll
    for (int kk = 0; kk < 4; kk++) {
      const int kt = kk >> 1, jA = 4 * (kk & 1);
      union { u32 u[4]; bf16x8 v; } pfg;
      pfg.u[0] = hi ? dx[kt][jA + 2] : c[kt][jA];
      pfg.u[1] = hi ? dx[kt][jA + 3] : c[kt][jA + 1];
      pfg.u[2] = hi ? c[kt][jA + 2]  : dx[kt][jA];
      pfg.u[3] = hi ? c[kt][jA + 3]  : dx[kt][jA + 1];
#pragma unroll
      for (int dt = 0; dt < 2; dt++) {
        bf16x8 va = *(const bf16x8*)&Vtlds[(dt * 32 + l31) * LDSS + kk * 16 + hi * 8];
        o[dt] = __builtin_amdgcn_mfma_f32_32x32x16_bf16(va, pfg.v, o[dt], 0, 0, 0);
      }
    }
    __builtin_amdgcn_s_setprio(0);
  }

  // normalize + write O (b, n, h*64+d): d = dt*32 + 8g + 4hi + j
  float inv = 1.0f / lrow;
  size_t obase = (size_t)(b * 2048 + qrow) * 512 + h * 64;
#pragma unroll
  for (int dt = 0; dt < 2; dt++)
#pragma unroll
    for (int g = 0; g < 4; g++) {
      uint2 pr;
      pr.x = cvt_pk_bf16(o[dt][4 * g + 0] * inv, o[dt][4 * g + 1] * inv);
      pr.y = cvt_pk_bf16(o[dt][4 * g + 2] * inv, o[dt][4 * g + 3] * inv);
      *(uint2*)&O[obase + dt * 32 + 8 * g + 4 * hi] = pr;
    }
}

// ---------------- output projection (reg-prefetch pipelined) ----------------
__global__ __launch_bounds__(256) void outproj_kernel(
    const u16* __restrict__ Ob, const u16* __restrict__ woT,
    const float* __restrict__ bo, float* __restrict__ out) {
  __shared__ u16 Alds[64 * LDSS];
  __shared__ u16 Blds[64 * LDSS];
  int m0 = blockIdx.y * 64;
  int n0 = blockIdx.x * 64;
  int tid = threadIdx.x;
  int lane = tid & 63, w = tid >> 6;
  int wm = w >> 1, wn = w & 1;
  int l15 = lane & 15, l4 = lane >> 4;

  int r0 = tid >> 3, c8 = (tid & 7) * 8;
  uint4 ar0 = *(const uint4*)&Ob[(m0 + r0) * 512 + c8];
  uint4 ar1 = *(const uint4*)&Ob[(m0 + r0 + 32) * 512 + c8];
  uint4 br0 = *(const uint4*)&woT[(n0 + r0) * 512 + c8];
  uint4 br1 = *(const uint4*)&woT[(n0 + r0 + 32) * 512 + c8];

  f32x4 acc[2][2] = {};
  for (int ks = 0; ks < 8; ks++) {
    __syncthreads();
    *(uint4*)&Alds[r0 * LDSS + c8]        = ar0;
    *(uint4*)&Alds[(r0 + 32) * LDSS + c8] = ar1;
    *(uint4*)&Blds[r0 * LDSS + c8]        = br0;
    *(uint4*)&Blds[(r0 + 32) * LDSS + c8] = br1;
    __syncthreads();
    if (ks < 7) {
      int k0 = (ks + 1) * 64;
      ar0 = *(const uint4*)&Ob[(m0 + r0) * 512 + k0 + c8];
      ar1 = *(const uint4*)&Ob[(m0 + r0 + 32) * 512 + k0 + c8];
      br0 = *(const uint4*)&woT[(n0 + r0) * 512 + k0 + c8];
      br1 = *(const uint4*)&woT[(n0 + r0 + 32) * 512 + k0 + c8];
    }
#pragma unroll
    for (int kk = 0; kk < 2; kk++) {
      bf16x8 a[2], bfr[2];
#pragma unroll
      for (int f = 0; f < 2; f++) {
        a[f] = *(const bf16x8*)&Alds[(wm * 32 + f * 16 + l15) * LDSS + kk * 32 + l4 * 8];
        bfr[f] = *(const bf16x8*)&Blds[(wn * 32 + f * 16 + l15) * LDSS + kk * 32 + l4 * 8];
      }
#pragma unroll
      for (int fm = 0; fm < 2; fm++)
#pragma unroll
        for (int fn = 0; fn < 2; fn++)
          acc[fm][fn] = __builtin_amdgcn_mfma_f32_16x16x32_bf16(a[fm], bfr[fn], acc[fm][fn], 0, 0, 0);
    }
  }
#pragma unroll
  for (int fm = 0; fm < 2; fm++)
#pragma unroll
    for (int fn = 0; fn < 2; fn++)
#pragma unroll
      for (int r = 0; r < 4; r++) {
        int row = wm * 32 + fm * 16 + l4 * 4 + r;
        int col = wn * 32 + fn * 16 + l15;
        out[(size_t)(m0 + row) * 512 + n0 + col] = acc[fm][fn][r] + bo[n0 + col];
      }
}

extern "C" void kernel_launch(void* const* d_in, const int* in_sizes, int n_in,
                              void* d_out, int out_size, void* d_ws, size_t ws_size,
                              hipStream_t stream) {
  const float* x    = (const float*)d_in[0];
  const float* bias = (const float*)d_in[1];
  const float* wq   = (const float*)d_in[2];
  const float* bq   = (const float*)d_in[3];
  const float* wk   = (const float*)d_in[4];
  const float* bk   = (const float*)d_in[5];
  const float* wv   = (const float*)d_in[6];
  const float* bv   = (const float*)d_in[7];
  const float* wo   = (const float*)d_in[8];
  const float* bo   = (const float*)d_in[9];
  float* out = (float*)d_out;

  char* ws = (char*)d_ws;
  u16* xb  = (u16*)(ws + 0);
  u16* wqT = (u16*)(ws + 8388608);
  u16* wkT = (u16*)(ws + 8912896);
  u16* wvT = (u16*)(ws + 9437184);
  u16* woT = (u16*)(ws + 9961472);
  u16* Qb  = (u16*)(ws + 10485760);
  u16* Kb  = (u16*)(ws + 18874368);
  u16* VtB = (u16*)(ws + 27262976);
  u16* Ob  = (u16*)(ws + 35651584);

  hipLaunchKernelGGL(cast_x_kernel, dim3(2048), dim3(256), 0, stream, x, xb);
  hipLaunchKernelGGL(cast_wT_kernel, dim3(4096), dim3(256), 0, stream,
                     wq, wk, wv, wo, wqT, wkT, wvT, woT);
  hipLaunchKernelGGL(proj_kernel, dim3(8, 128, 3), dim3(256), 0, stream,
                     xb, wqT, wkT, wvT, bq, bk, bv, Qb, Kb, VtB);
  hipLaunchKernelGGL(attn_kernel, dim3(16, 8, 4), dim3(256), 0, stream,
                     Qb, Kb, VtB, bias, Ob);
  hipLaunchKernelGGL(outproj_kernel, dim3(8, 128), dim3(256), 0, stream,
                     Ob, woT, bo, out);
}